// Round 14
// baseline (206.937 us; speedup 1.0000x reference)
//
#include <hip/hip_runtime.h>

// Wav2Vec2 Gumbel VQ — round 14: 128-row tiles to halve LDS traffic per output
// (r13 diagnosis: LDS port ~630cyc/chunk was the wall, not DMA latency).
// 1024 blocks (128 rows x 1 group), 8 waves = 2rh x 4hc, 20 MFMA/chunk/wave.
// 4 LDS buffers (112KB), depth-3 DMA, exact counted vmcnt, (512,2) no-spill.

#define GG   2
#define KK   320
#define NN   65536
#define DD   512
#define DPG  128
#define EPSL 1e-7f
#define NCPY 8
#define BUFB 28672   // 28 frags/chunk: 8 A + 20 B

typedef __attribute__((ext_vector_type(8))) short bf16x8;   // 8 x bf16
typedef __attribute__((ext_vector_type(4))) float f32x4;
typedef __attribute__((address_space(1))) void glb_void;
typedef __attribute__((address_space(3))) void lds_void;

static __device__ __forceinline__ unsigned short f2bf_rne(float f) {
    unsigned u = __float_as_uint(f);
    u += 0x7FFFu + ((u >> 16) & 1u);
    return (unsigned short)(u >> 16);
}

static __device__ __forceinline__ bf16x8 pack8_rne(float4 v0, float4 v1) {
    union { unsigned short s[8]; bf16x8 b; } u;
    u.s[0] = f2bf_rne(v0.x); u.s[1] = f2bf_rne(v0.y);
    u.s[2] = f2bf_rne(v0.z); u.s[3] = f2bf_rne(v0.w);
    u.s[4] = f2bf_rne(v1.x); u.s[5] = f2bf_rne(v1.y);
    u.s[6] = f2bf_rne(v1.z); u.s[7] = f2bf_rne(v1.w);
    return u.b;
}

// ---------- fused prep: H->Hbf (blocks 0..16383), W->Wf (16384..16543), marg zero ----------
// Hbf[tile32][f=rf*16+t][l]: row = tile*32 + 16rf + (l&15), k = 32t + 8(l>>4)+j
// Wf frag w = ct*16+t: (w*512 + l*8 + j) = W[col=16ct+(l&15)][k=32t+8(l>>4)+j]
__global__ __launch_bounds__(256) void prep_all(
    const float* __restrict__ H, short* __restrict__ Hbf,
    const float* __restrict__ W, short* __restrict__ Wf,
    float* __restrict__ marg)
{
    const int b = blockIdx.x, tid = threadIdx.x;
    if (b < 16384) {
        int gt = b * 256 + tid;
        int tile = gt >> 11, f = (gt >> 6) & 31, l = gt & 63;
        int rf = f >> 4, t = f & 15;
        const float* src = H + (size_t)(tile * 32 + 16 * rf + (l & 15)) * DD + 32 * t + 8 * (l >> 4);
        float4 v0 = *(const float4*)src;
        float4 v1 = *(const float4*)(src + 4);
        *(bf16x8*)(Hbf + (size_t)gt * 8) = pack8_rne(v0, v1);
    } else if (b < 16544) {
        int gt = (b - 16384) * 256 + tid;
        int w  = gt >> 6, l = gt & 63;
        int col = 16 * (w >> 4) + (l & 15);
        int k0  = 32 * (w & 15) + 8 * (l >> 4);
        const float* src = W + (size_t)col * DD + k0;
        float4 v0 = *(const float4*)(src);
        float4 v1 = *(const float4*)(src + 4);
        *(bf16x8*)(Wf + (size_t)w * 512 + (size_t)l * 8) = pack8_rne(v0, v1);
    } else {
        for (int i = tid; i < NCPY * GG * KK; i += 256) marg[i] = 0.f;
    }
}

// ---------- main: GEMM + softmax/argmax/marginal (writes idx + marg only) ----------
// grid 1024 = 512 row-tiles (128 rows) x 2 groups; 512 thr = 8 waves.
// wave wid: rh = wid>>2 (64-row half), hc = wid&3 (col quarter): 4 rf x 5 cf.
__global__ __launch_bounds__(512, 2) void vq_main(
    const short* Hbf, const int* __restrict__ mask,
    const float* __restrict__ gumbel, const short* __restrict__ Wf,
    const float* __restrict__ bias, const float* __restrict__ cv,
    int* __restrict__ idxW, float* __restrict__ marg)
{
    __shared__ __align__(16) char smem[4 * BUFB];     // 112 KB: 4 chunk buffers
    __shared__ float red_s[512], red_z[512];
    __shared__ int   red_i[512];
    __shared__ float wrowS[128];

    const int tid = threadIdx.x;
    const int l   = tid & 63, wid = tid >> 6;
    const int rh  = wid >> 2, hc = wid & 3;
    const int g   = blockIdx.x & 1;
    const int RT  = blockIdx.x >> 1;
    const int n0  = RT * 128;
    const int q   = l >> 4,  ln = l & 15;

    // chunk frag list (28): fi<8 -> A row-frag fi; fi>=8 -> B col-frag b=fi-8.
    // wave wid stages fi = wid + 8*j, j=0..3 (waves 0-3: 4 frags, 4-7: 3).
#define ISSUE(t_, b_)                                                          \
    { _Pragma("unroll")                                                        \
      for (int j = 0; j < 4; ++j) {                                            \
          const int fi = wid + 8 * j;                                          \
          if (fi < 28) {                                                       \
              size_t soff;                                                     \
              const short* gb;                                                 \
              if (fi < 8) { soff = (size_t)((RT * 4 + (fi >> 1)) * 32 + (fi & 1) * 16 + (t_)) * 512; gb = Hbf; } \
              else        { soff = (size_t)((g * 20 + (fi - 8)) * 16 + (t_)) * 512;                 gb = Wf;  } \
              const short* gsrc = gb + soff + (size_t)l * 8;                   \
              char* ldst = smem + (b_)*BUFB + fi * 1024;                       \
              __builtin_amdgcn_global_load_lds((const glb_void*)gsrc, (lds_void*)ldst, 16, 0, 0); \
          }                                                                    \
      } }

    f32x4 acc[4][5];
    const f32x4 vzero = {0.f, 0.f, 0.f, 0.f};
#pragma unroll
    for (int a = 0; a < 4; ++a)
#pragma unroll
        for (int b = 0; b < 5; ++b) acc[a][b] = vzero;

#define COMPUTE(b_)                                                            \
    { const char* bb_ = smem + (b_)*BUFB;                                      \
      bf16x8 Ar[4], Br[5];                                                     \
      _Pragma("unroll")                                                        \
      for (int rf = 0; rf < 4; ++rf)                                           \
          Ar[rf] = *(const bf16x8*)(bb_ + (rh * 4 + rf) * 1024 + l * 16);      \
      _Pragma("unroll")                                                        \
      for (int cf = 0; cf < 5; ++cf)                                           \
          Br[cf] = *(const bf16x8*)(bb_ + (8 + hc * 5 + cf) * 1024 + l * 16);  \
      __builtin_amdgcn_s_setprio(1);                                           \
      _Pragma("unroll")                                                        \
      for (int cf = 0; cf < 5; ++cf)                                           \
          _Pragma("unroll")                                                    \
          for (int rf = 0; rf < 4; ++rf)                                       \
              acc[rf][cf] = __builtin_amdgcn_mfma_f32_16x16x32_bf16(Ar[rf], Br[cf], acc[rf][cf], 0, 0, 0); \
      __builtin_amdgcn_s_setprio(0); }

    // depth-3: buffers cycle %4; chunk c+3 issued after barrier of iter c
    // (buf (c+3)%4 free: chunk c-1 consumed before that barrier).
    ISSUE(0, 0)
    ISSUE(1, 1)
    ISSUE(2, 2)
#pragma unroll 1
    for (int c = 0; c < 16; ++c) {
        // exact per-wave counted wait: batch nb = (wid<4)?4:3; outstanding
        // batches = min(3, 16-c); wait until (outstanding-1) batches remain.
        if (c < 14) {
            if (wid < 4) asm volatile("s_waitcnt vmcnt(8)" ::: "memory");
            else         asm volatile("s_waitcnt vmcnt(6)" ::: "memory");
        } else if (c == 14) {
            if (wid < 4) asm volatile("s_waitcnt vmcnt(4)" ::: "memory");
            else         asm volatile("s_waitcnt vmcnt(3)" ::: "memory");
        } else {
            asm volatile("s_waitcnt vmcnt(0)" ::: "memory");
        }
        __builtin_amdgcn_sched_barrier(0);
        __builtin_amdgcn_s_barrier();                  // raw: no vmcnt(0) drain
        if (c + 3 < 16) ISSUE(c + 3, (c + 3) & 3)
        __builtin_amdgcn_sched_barrier(0);
        COMPUTE(c & 3)
    }

    // ---- epilogue: bias + gumbel, no-max softmax (exp into acc), argmax ----
    float bb[5];
#pragma unroll
    for (int cf = 0; cf < 5; ++cf) bb[cf] = bias[g * KK + hc * 80 + 16 * cf + ln];

    float gum[16][5];
#pragma unroll
    for (int rf = 0; rf < 4; ++rf)
#pragma unroll
        for (int reg = 0; reg < 4; ++reg) {
            const int row = (rh * 4 + rf) * 16 + 4 * q + reg;
            const float* gp = gumbel + ((size_t)(n0 + row) * GG + g) * KK + hc * 80 + ln;
#pragma unroll
            for (int cf = 0; cf < 5; ++cf) gum[rf * 4 + reg][cf] = gp[16 * cf];
        }
    __builtin_amdgcn_sched_barrier(0);

#pragma unroll
    for (int cf = 0; cf < 5; ++cf)
#pragma unroll
        for (int rf = 0; rf < 4; ++rf) {
            acc[rf][cf][0] += bb[cf]; acc[rf][cf][1] += bb[cf];
            acc[rf][cf][2] += bb[cf]; acc[rf][cf][3] += bb[cf];
        }

#pragma unroll
    for (int rf = 0; rf < 4; ++rf) {
#pragma unroll
        for (int reg = 0; reg < 4; ++reg) {
            const int row = (rh * 4 + rf) * 16 + 4 * q + reg;
            float s = 0.f, zm = -3.0e38f;
            int zi = 0;
#pragma unroll
            for (int cf = 0; cf < 5; ++cf) {
                float v = acc[rf][cf][reg];
                float z = v + gum[rf * 4 + reg][cf];
                if (z > zm) { zm = z; zi = hc * 80 + 16 * cf + ln; }  // first-index tie rule
                float e = __expf(v);
                s += e;
                acc[rf][cf][reg] = e;              // reuse in marginal
            }
#pragma unroll
            for (int d = 1; d <= 8; d <<= 1) {
                s += __shfl_xor(s, d);
                float zo = __shfl_xor(zm, d);
                int   io = __shfl_xor(zi, d);
                if (zo > zm || (zo == zm && io < zi)) { zm = zo; zi = io; }
            }
            if (ln == 0) {
                const int base = row * 4 + hc;
                red_s[base] = s;
                red_z[base] = zm; red_i[base] = zi;
            }
        }
    }
    __syncthreads();

    if (tid < 128) {
        const int b0 = tid * 4;
        float Z = red_s[b0] + red_s[b0 + 1] + red_s[b0 + 2] + red_s[b0 + 3];
        float zb = -3.0e38f; int ib = 0;
#pragma unroll
        for (int h = 0; h < 4; ++h)
            if (red_z[b0 + h] > zb) { zb = red_z[b0 + h]; ib = red_i[b0 + h]; }  // ascending h: first max wins
        idxW[(size_t)(n0 + tid) * GG + g] = ib;
        wrowS[tid] = ((mask[n0 + tid] != 0) ? 1.0f : 0.0f) / Z;
    }
    __syncthreads();

    // ---- marginal (acc holds exp) ----
    float cs[5] = {0.f, 0.f, 0.f, 0.f, 0.f};
#pragma unroll
    for (int rf = 0; rf < 4; ++rf) {
#pragma unroll
        for (int reg = 0; reg < 4; ++reg) {
            const int row = (rh * 4 + rf) * 16 + 4 * q + reg;
            const float wv = wrowS[row];
#pragma unroll
            for (int cf = 0; cf < 5; ++cf)
                cs[cf] += acc[rf][cf][reg] * wv;
        }
    }
    {
        float* mc = marg + (size_t)(blockIdx.x & (NCPY - 1)) * (GG * KK);
#pragma unroll
        for (int cf = 0; cf < 5; ++cf) {
            float v = cs[cf];
            v += __shfl_xor(v, 16);
            v += __shfl_xor(v, 32);
            if (l < 16) atomicAdd(&mc[g * KK + hc * 80 + 16 * cf + l], v);
        }
    }
}

// ---------- gather: out[n, g*128+d] = cv[g, idx[n,g], d] ----------
__global__ __launch_bounds__(256) void gather_kernel(
    const int* __restrict__ idxW, const float* __restrict__ cv,
    float* __restrict__ out)
{
    const int e = blockIdx.x * 256 + threadIdx.x;     // 4,194,304 float4 slots
    const int n = e >> 6, s4 = e & 63, g = s4 >> 5, d4 = s4 & 31;
    const int idx = idxW[(size_t)n * GG + g];
    const float4 v = ((const float4*)cv)[((size_t)g * KK + idx) * 32 + d4];
    ((float4*)out)[e] = v;
}

// ---------- perplexity finalize ----------
__global__ __launch_bounds__(256) void finalize_kernel(
    const int* __restrict__ mask, const float* __restrict__ marg,
    float* __restrict__ perp_out)
{
    __shared__ float red[256];
    __shared__ float hg[GG];
    const int tid = threadIdx.x;

    int cnt = 0;
    for (int n = tid; n < NN; n += 256) cnt += (mask[n] != 0) ? 1 : 0;
    red[tid] = (float)cnt;
    __syncthreads();
    for (int s = 128; s > 0; s >>= 1) {
        if (tid < s) red[tid] += red[tid + s];
        __syncthreads();
    }
    const float invc = 1.0f / red[0];
    __syncthreads();

    for (int g = 0; g < GG; ++g) {
        float h = 0.0f;
        for (int c = tid; c < KK; c += 256) {
            float m = 0.f;
#pragma unroll
            for (int x = 0; x < NCPY; ++x) m += marg[x * (GG * KK) + g * KK + c];
            m *= invc;
            h += m * logf(m + EPSL);
        }
        red[tid] = h;
        __syncthreads();
        for (int s = 128; s > 0; s >>= 1) {
            if (tid < s) red[tid] += red[tid + s];
            __syncthreads();
        }
        if (tid == 0) hg[g] = red[0];
        __syncthreads();
    }
    if (tid == 0) perp_out[0] = expf(-hg[0]) + expf(-hg[1]);
}

extern "C" void kernel_launch(void* const* d_in, const int* in_sizes, int n_in,
                              void* d_out, int out_size, void* d_ws, size_t ws_size,
                              hipStream_t stream)
{
    const float* H      = (const float*)d_in[0];   // (32,2048,512) f32
    const int*   mask   = (const int*)d_in[1];     // (32,2048) bool->int32
    const float* gumbel = (const float*)d_in[2];   // (131072,320) f32
    const float* W      = (const float*)d_in[3];   // (640,512) f32
    const float* bias   = (const float*)d_in[4];   // (640,) f32
    const float* cv     = (const float*)d_in[5];   // (1,640,128) f32

    float*  out  = (float*)d_out;                  // 16,777,216 + 1 floats
    short*  Hbf  = (short*)d_out;                  // frag-ordered bf16 H (64 MiB)
    float*  marg = (float*)d_ws;                   // 8 copies x 640 f32 (20 KB)
    short*  Wf   = (short*)((char*)d_ws + 32768);  // 0.655 MB bf16 frags
    int*    idxW = (int*)((char*)d_ws + 32768 + 655360);  // 131072 ints

    prep_all<<<16545, 256, 0, stream>>>(H, Hbf, W, Wf, marg);
    vq_main<<<1024, 512, 0, stream>>>(Hbf, mask, gumbel, Wf, bias, cv, idxW, marg);
    gather_kernel<<<16384, 256, 0, stream>>>(idxW, cv, out);
    finalize_kernel<<<1, 256, 0, stream>>>(mask, marg, out + (size_t)NN * GG * DPG);
}

// Round 15
// 169.764 us; speedup vs baseline: 1.2190x; 1.2190x over previous
//
#include <hip/hip_runtime.h>

// Wav2Vec2 Gumbel VQ — round 15: (1) prep_h rebuilt as coalesced wave-transpose
// (row-contiguous 32B reads -> RNE pack -> ds_bpermute redistribute -> coalesced
// frag write); (2) vq_main = r12's proven 106us schedule (ISSUE-then-wait, 3 buf)
// + r13 exp-reuse epilogue; (3) finalize fused into gather (block 0).

#define GG   2
#define KK   320
#define NN   65536
#define DD   512
#define DPG  128
#define EPSL 1e-7f
#define NCPY 8
#define BUFB 24576   // bytes per LDS chunk buffer: 4 A frags + 20 B frags

typedef __attribute__((ext_vector_type(8))) short bf16x8;   // 8 x bf16
typedef __attribute__((ext_vector_type(4))) float f32x4;
typedef __attribute__((address_space(1))) void glb_void;
typedef __attribute__((address_space(3))) void lds_void;

static __device__ __forceinline__ unsigned short f2bf_rne(float f) {
    unsigned u = __float_as_uint(f);
    u += 0x7FFFu + ((u >> 16) & 1u);
    return (unsigned short)(u >> 16);
}

static __device__ __forceinline__ bf16x8 pack8_rne(float4 v0, float4 v1) {
    union { unsigned short s[8]; bf16x8 b; } u;
    u.s[0] = f2bf_rne(v0.x); u.s[1] = f2bf_rne(v0.y);
    u.s[2] = f2bf_rne(v0.z); u.s[3] = f2bf_rne(v0.w);
    u.s[4] = f2bf_rne(v1.x); u.s[5] = f2bf_rne(v1.y);
    u.s[6] = f2bf_rne(v1.z); u.s[7] = f2bf_rne(v1.w);
    return u.b;
}

// ---------- fused prep ----------
// blocks 0..16383: H -> Hbf, one frag per wave (4 frags/block).
//   Frag F: tile=F>>5, f=F&31 (rf=f>>4, t=f&15); covers rows tile*32+rf*16..+16,
//   k 32t..32t+32. Source lane ls reads row tb+(ls>>2), k-seg (ls&3) (32B,
//   row-contiguous -> coalesced 128B bursts). Output lane lo needs row tb+(lo&15),
//   k-group lo>>4  =>  pull from ls = 4*(lo&15) + (lo>>4) via ds_bpermute.
// blocks 16384..16543: W -> Wf (unchanged layout). block 16544: zero marg.
__global__ __launch_bounds__(256) void prep_all(
    const float* __restrict__ H, short* __restrict__ Hbf,
    const float* __restrict__ W, short* __restrict__ Wf,
    float* __restrict__ marg)
{
    const int b = blockIdx.x, tid = threadIdx.x;
    if (b < 16384) {
        const int F = b * 4 + (tid >> 6);        // 65536 frags
        const int l = tid & 63;
        const int tile = F >> 5, f = F & 31;
        const int rf = f >> 4, t = f & 15;
        const int row = tile * 32 + rf * 16 + (l >> 2);
        const float* src = H + (size_t)row * DD + t * 32 + (l & 3) * 8;
        float4 v0 = *(const float4*)src;
        float4 v1 = *(const float4*)(src + 4);
        union { unsigned short s[8]; int d[4]; } u;
        u.s[0] = f2bf_rne(v0.x); u.s[1] = f2bf_rne(v0.y);
        u.s[2] = f2bf_rne(v0.z); u.s[3] = f2bf_rne(v0.w);
        u.s[4] = f2bf_rne(v1.x); u.s[5] = f2bf_rne(v1.y);
        u.s[6] = f2bf_rne(v1.z); u.s[7] = f2bf_rne(v1.w);
        const int ls4 = (4 * (l & 15) + (l >> 4)) * 4;
        int4 o;
        o.x = __builtin_amdgcn_ds_bpermute(ls4, u.d[0]);
        o.y = __builtin_amdgcn_ds_bpermute(ls4, u.d[1]);
        o.z = __builtin_amdgcn_ds_bpermute(ls4, u.d[2]);
        o.w = __builtin_amdgcn_ds_bpermute(ls4, u.d[3]);
        *(int4*)(Hbf + (size_t)F * 512 + (size_t)l * 8) = o;
    } else if (b < 16544) {
        int gt = (b - 16384) * 256 + tid;
        int w  = gt >> 6, l = gt & 63;
        int col = 16 * (w >> 4) + (l & 15);
        int k0  = 32 * (w & 15) + 8 * (l >> 4);
        const float* src = W + (size_t)col * DD + k0;
        float4 v0 = *(const float4*)(src);
        float4 v1 = *(const float4*)(src + 4);
        *(bf16x8*)(Wf + (size_t)w * 512 + (size_t)l * 8) = pack8_rne(v0, v1);
    } else {
        for (int i = tid; i < NCPY * GG * KK; i += 256) marg[i] = 0.f;
    }
}

// ---------- main: GEMM + softmax/argmax/marginal (writes idx + marg only) ----------
// grid 2048 = 1024 row-tiles (64 rows) x 2 groups; 512 thr = 8 waves.
// wave wid: rh = wid>>2 (row half), hc = wid&3 (col quarter, 5 cf x 16 cols).
// r12 schedule (measured 106us): ISSUE(c+1) -> vmcnt(3) -> s_barrier -> COMPUTE(c).
__global__ __launch_bounds__(512, 4) void vq_main(
    const short* Hbf, const int* __restrict__ mask,
    const float* __restrict__ gumbel, const short* __restrict__ Wf,
    const float* __restrict__ bias, const float* __restrict__ cv,
    int* __restrict__ idxW, float* __restrict__ marg)
{
    __shared__ __align__(16) char smem[3 * BUFB];     // 72 KB: 3 chunk buffers
    __shared__ float red_s[256], red_z[256];
    __shared__ int   red_i[256];
    __shared__ float wrowS[64];

    const int tid = threadIdx.x;
    const int l   = tid & 63, wid = tid >> 6;
    const int rh  = wid >> 2, hc = wid & 3;
    const int g   = blockIdx.x & 1;
    const int T   = blockIdx.x >> 1;
    const int n0  = T * 64;
    const int q   = l >> 4,  ln = l & 15;

    // per-chunk frag list (24): k<4 -> A frag (s=k>>1, rf=k&1); else B frag ct=k-4.
    // wave wid stages k = wid*3 + {0,1,2}; per-lane src = frag base + l*16 bytes.
    // LDS dst = buf + k*1024 (wave-uniform base; HW adds lane*16).
#define ISSUE(t_, b_)                                                          \
    { _Pragma("unroll")                                                        \
      for (int j = 0; j < 3; ++j) {                                            \
          const int k = wid * 3 + j;                                           \
          size_t soff;                                                         \
          const short* gb;                                                     \
          if (k < 4) { soff = (size_t)((2 * T + (k >> 1)) * 32 + (k & 1) * 16 + (t_)) * 512; gb = Hbf; } \
          else       { soff = (size_t)((g * 20 + (k - 4)) * 16 + (t_)) * 512;               gb = Wf;  } \
          const short* gsrc = gb + soff + (size_t)l * 8;                       \
          char* ldst = smem + (b_)*BUFB + k * 1024;                            \
          __builtin_amdgcn_global_load_lds((const glb_void*)gsrc, (lds_void*)ldst, 16, 0, 0); \
      } }

    f32x4 acc[2][5];
    const f32x4 vzero = {0.f, 0.f, 0.f, 0.f};
#pragma unroll
    for (int a = 0; a < 2; ++a)
#pragma unroll
        for (int b = 0; b < 5; ++b) acc[a][b] = vzero;

#define COMPUTE(b_)                                                            \
    { const char* bb_ = smem + (b_)*BUFB;                                      \
      bf16x8 Ar[2], Br[5];                                                     \
      _Pragma("unroll")                                                        \
      for (int rf = 0; rf < 2; ++rf)                                           \
          Ar[rf] = *(const bf16x8*)(bb_ + (rh * 2 + rf) * 1024 + l * 16);      \
      _Pragma("unroll")                                                        \
      for (int cf = 0; cf < 5; ++cf)                                           \
          Br[cf] = *(const bf16x8*)(bb_ + 4096 + (hc * 5 + cf) * 1024 + l * 16); \
      __builtin_amdgcn_s_setprio(1);                                           \
      _Pragma("unroll")                                                        \
      for (int cf = 0; cf < 5; ++cf) {                                         \
          acc[0][cf] = __builtin_amdgcn_mfma_f32_16x16x32_bf16(Ar[0], Br[cf], acc[0][cf], 0, 0, 0); \
          acc[1][cf] = __builtin_amdgcn_mfma_f32_16x16x32_bf16(Ar[1], Br[cf], acc[1][cf], 0, 0, 0); } \
      __builtin_amdgcn_s_setprio(0); }

    ISSUE(0, 0)
#pragma unroll 1
    for (int c = 0; c < 15; ++c) {
        ISSUE(c + 1, (c + 1) % 3)
        asm volatile("s_waitcnt vmcnt(3)" ::: "memory");   // chunk c landed; c+1 in flight
        __builtin_amdgcn_sched_barrier(0);
        __builtin_amdgcn_s_barrier();                      // raw: no vmcnt(0) drain
        COMPUTE(c % 3)
    }
    asm volatile("s_waitcnt vmcnt(0)" ::: "memory");
    __builtin_amdgcn_sched_barrier(0);
    __builtin_amdgcn_s_barrier();
    COMPUTE(0)                                             // chunk 15 -> buf 15%3 == 0

    // ---- epilogue: bias + gumbel, no-max softmax (exp into acc), argmax ----
    float bb[5];
#pragma unroll
    for (int cf = 0; cf < 5; ++cf) bb[cf] = bias[g * KK + hc * 80 + 16 * cf + ln];

    float gum[8][5];
#pragma unroll
    for (int rf = 0; rf < 2; ++rf)
#pragma unroll
        for (int reg = 0; reg < 4; ++reg) {
            const int row = 32 * rh + 16 * rf + 4 * q + reg;
            const float* gp = gumbel + ((size_t)(n0 + row) * GG + g) * KK + hc * 80 + ln;
#pragma unroll
            for (int cf = 0; cf < 5; ++cf) gum[rf * 4 + reg][cf] = gp[16 * cf];
        }
    __builtin_amdgcn_sched_barrier(0);

#pragma unroll
    for (int cf = 0; cf < 5; ++cf)
#pragma unroll
        for (int rf = 0; rf < 2; ++rf) {
            acc[rf][cf][0] += bb[cf]; acc[rf][cf][1] += bb[cf];
            acc[rf][cf][2] += bb[cf]; acc[rf][cf][3] += bb[cf];
        }

#pragma unroll
    for (int rf = 0; rf < 2; ++rf) {
#pragma unroll
        for (int reg = 0; reg < 4; ++reg) {
            const int row = 32 * rh + 16 * rf + 4 * q + reg;
            float s = 0.f, zm = -3.0e38f;
            int zi = 0;
#pragma unroll
            for (int cf = 0; cf < 5; ++cf) {
                float v = acc[rf][cf][reg];
                float z = v + gum[rf * 4 + reg][cf];
                if (z > zm) { zm = z; zi = hc * 80 + 16 * cf + ln; }  // first-index tie rule
                float e = __expf(v);
                s += e;
                acc[rf][cf][reg] = e;              // reuse in marginal
            }
#pragma unroll
            for (int d = 1; d <= 8; d <<= 1) {
                s += __shfl_xor(s, d);
                float zo = __shfl_xor(zm, d);
                int   io = __shfl_xor(zi, d);
                if (zo > zm || (zo == zm && io < zi)) { zm = zo; zi = io; }
            }
            if (ln == 0) {
                const int base = row * 4 + hc;
                red_s[base] = s;
                red_z[base] = zm; red_i[base] = zi;
            }
        }
    }
    __syncthreads();

    if (tid < 64) {
        const int b0 = tid * 4;
        float Z = red_s[b0] + red_s[b0 + 1] + red_s[b0 + 2] + red_s[b0 + 3];
        float zb = -3.0e38f; int ib = 0;
#pragma unroll
        for (int h = 0; h < 4; ++h)
            if (red_z[b0 + h] > zb) { zb = red_z[b0 + h]; ib = red_i[b0 + h]; }  // ascending h: first max wins
        idxW[(size_t)(n0 + tid) * GG + g] = ib;
        wrowS[tid] = ((mask[n0 + tid] != 0) ? 1.0f : 0.0f) / Z;
    }
    __syncthreads();

    // ---- marginal (acc already holds exp) ----
    float cs[5] = {0.f, 0.f, 0.f, 0.f, 0.f};
#pragma unroll
    for (int rf = 0; rf < 2; ++rf) {
#pragma unroll
        for (int reg = 0; reg < 4; ++reg) {
            const int row = 32 * rh + 16 * rf + 4 * q + reg;
            const float wv = wrowS[row];
#pragma unroll
            for (int cf = 0; cf < 5; ++cf)
                cs[cf] += acc[rf][cf][reg] * wv;
        }
    }
    {
        float* mc = marg + (size_t)(blockIdx.x & (NCPY - 1)) * (GG * KK);
#pragma unroll
        for (int cf = 0; cf < 5; ++cf) {
            float v = cs[cf];
            v += __shfl_xor(v, 16);
            v += __shfl_xor(v, 32);
            if (l < 16) atomicAdd(&mc[g * KK + hc * 80 + 16 * cf + l], v);
        }
    }
}

// ---------- gather (blocks 1..16384) + fused finalize (block 0) ----------
__global__ __launch_bounds__(256) void gather_fin(
    const int* __restrict__ idxW, const float* __restrict__ cv,
    float* __restrict__ out,
    const int* __restrict__ mask, const float* __restrict__ marg,
    float* __restrict__ perp_out)
{
    const int tid = threadIdx.x;
    if (blockIdx.x == 0) {
        __shared__ float red[256];
        __shared__ float hg[GG];
        int cnt = 0;
        for (int n = tid; n < NN; n += 256) cnt += (mask[n] != 0) ? 1 : 0;
        red[tid] = (float)cnt;
        __syncthreads();
        for (int s = 128; s > 0; s >>= 1) {
            if (tid < s) red[tid] += red[tid + s];
            __syncthreads();
        }
        const float invc = 1.0f / red[0];
        __syncthreads();
        for (int g = 0; g < GG; ++g) {
            float h = 0.0f;
            for (int c = tid; c < KK; c += 256) {
                float m = 0.f;
#pragma unroll
                for (int x = 0; x < NCPY; ++x) m += marg[x * (GG * KK) + g * KK + c];
                m *= invc;
                h += m * logf(m + EPSL);
            }
            red[tid] = h;
            __syncthreads();
            for (int s = 128; s > 0; s >>= 1) {
                if (tid < s) red[tid] += red[tid + s];
                __syncthreads();
            }
            if (tid == 0) hg[g] = red[0];
            __syncthreads();
        }
        if (tid == 0) perp_out[0] = expf(-hg[0]) + expf(-hg[1]);
        return;
    }
    const int e = (blockIdx.x - 1) * 256 + tid;       // 4,194,304 float4 slots
    const int n = e >> 6, s4 = e & 63, g = s4 >> 5, d4 = s4 & 31;
    const int idx = idxW[(size_t)n * GG + g];
    const float4 v = ((const float4*)cv)[((size_t)g * KK + idx) * 32 + d4];
    ((float4*)out)[e] = v;
}

extern "C" void kernel_launch(void* const* d_in, const int* in_sizes, int n_in,
                              void* d_out, int out_size, void* d_ws, size_t ws_size,
                              hipStream_t stream)
{
    const float* H      = (const float*)d_in[0];   // (32,2048,512) f32
    const int*   mask   = (const int*)d_in[1];     // (32,2048) bool->int32
    const float* gumbel = (const float*)d_in[2];   // (131072,320) f32
    const float* W      = (const float*)d_in[3];   // (640,512) f32
    const float* bias   = (const float*)d_in[4];   // (640,) f32
    const float* cv     = (const float*)d_in[5];   // (1,640,128) f32

    float*  out  = (float*)d_out;                  // 16,777,216 + 1 floats
    short*  Hbf  = (short*)d_out;                  // frag-ordered bf16 H (64 MiB)
    float*  marg = (float*)d_ws;                   // 8 copies x 640 f32 (20 KB)
    short*  Wf   = (short*)((char*)d_ws + 32768);  // 0.655 MB bf16 frags
    int*    idxW = (int*)((char*)d_ws + 32768 + 655360);  // 131072 ints

    prep_all<<<16545, 256, 0, stream>>>(H, Hbf, W, Wf, marg);
    vq_main<<<2048, 512, 0, stream>>>(Hbf, mask, gumbel, Wf, bias, cv, idxW, marg);
    gather_fin<<<16385, 256, 0, stream>>>(idxW, cv, out, mask, marg,
                                          out + (size_t)NN * GG * DPG);
}

// Round 16
// 162.067 us; speedup vs baseline: 1.2769x; 1.0475x over previous
//
#include <hip/hip_runtime.h>

// Wav2Vec2 Gumbel VQ — round 16: (1) dual-path: if ws_size fits, Hbf lives in
// d_ws and vq_main fuses the codevector gather (out no longer aliases Hbf);
// else exact r15 fallback. (2) packed-key argmax butterfly (u32 max, 8 shfls
// vs 12 + cmp logic). (3) hoisted DMA base pointers.

#define GG   2
#define KK   320
#define NN   65536
#define DD   512
#define DPG  128
#define EPSL 1e-7f
#define NCPY 8
#define BUFB 24576   // bytes per LDS chunk buffer: 4 A frags + 20 B frags

typedef __attribute__((ext_vector_type(8))) short bf16x8;   // 8 x bf16
typedef __attribute__((ext_vector_type(4))) float f32x4;
typedef __attribute__((address_space(1))) void glb_void;
typedef __attribute__((address_space(3))) void lds_void;

static __device__ __forceinline__ unsigned short f2bf_rne(float f) {
    unsigned u = __float_as_uint(f);
    u += 0x7FFFu + ((u >> 16) & 1u);
    return (unsigned short)(u >> 16);
}

static __device__ __forceinline__ bf16x8 pack8_rne(float4 v0, float4 v1) {
    union { unsigned short s[8]; bf16x8 b; } u;
    u.s[0] = f2bf_rne(v0.x); u.s[1] = f2bf_rne(v0.y);
    u.s[2] = f2bf_rne(v0.z); u.s[3] = f2bf_rne(v0.w);
    u.s[4] = f2bf_rne(v1.x); u.s[5] = f2bf_rne(v1.y);
    u.s[6] = f2bf_rne(v1.z); u.s[7] = f2bf_rne(v1.w);
    return u.b;
}

// monotone uint map: f1 < f2  <=>  ordf(f1) < ordf(f2)
static __device__ __forceinline__ unsigned ordf(float f) {
    unsigned u = __float_as_uint(f);
    return (u & 0x80000000u) ? ~u : (u | 0x80000000u);
}

// ---------- fused prep (unchanged from r15: coalesced wave-transpose) ----------
__global__ __launch_bounds__(256) void prep_all(
    const float* __restrict__ H, short* __restrict__ Hbf,
    const float* __restrict__ W, short* __restrict__ Wf,
    float* __restrict__ marg)
{
    const int b = blockIdx.x, tid = threadIdx.x;
    if (b < 16384) {
        const int F = b * 4 + (tid >> 6);        // 65536 frags
        const int l = tid & 63;
        const int tile = F >> 5, f = F & 31;
        const int rf = f >> 4, t = f & 15;
        const int row = tile * 32 + rf * 16 + (l >> 2);
        const float* src = H + (size_t)row * DD + t * 32 + (l & 3) * 8;
        float4 v0 = *(const float4*)src;
        float4 v1 = *(const float4*)(src + 4);
        union { unsigned short s[8]; int d[4]; } u;
        u.s[0] = f2bf_rne(v0.x); u.s[1] = f2bf_rne(v0.y);
        u.s[2] = f2bf_rne(v0.z); u.s[3] = f2bf_rne(v0.w);
        u.s[4] = f2bf_rne(v1.x); u.s[5] = f2bf_rne(v1.y);
        u.s[6] = f2bf_rne(v1.z); u.s[7] = f2bf_rne(v1.w);
        const int ls4 = (4 * (l & 15) + (l >> 4)) * 4;
        int4 o;
        o.x = __builtin_amdgcn_ds_bpermute(ls4, u.d[0]);
        o.y = __builtin_amdgcn_ds_bpermute(ls4, u.d[1]);
        o.z = __builtin_amdgcn_ds_bpermute(ls4, u.d[2]);
        o.w = __builtin_amdgcn_ds_bpermute(ls4, u.d[3]);
        *(int4*)(Hbf + (size_t)F * 512 + (size_t)l * 8) = o;
    } else if (b < 16544) {
        int gt = (b - 16384) * 256 + tid;
        int w  = gt >> 6, l = gt & 63;
        int col = 16 * (w >> 4) + (l & 15);
        int k0  = 32 * (w & 15) + 8 * (l >> 4);
        const float* src = W + (size_t)col * DD + k0;
        float4 v0 = *(const float4*)(src);
        float4 v1 = *(const float4*)(src + 4);
        *(bf16x8*)(Wf + (size_t)w * 512 + (size_t)l * 8) = pack8_rne(v0, v1);
    } else {
        for (int i = tid; i < NCPY * GG * KK; i += 256) marg[i] = 0.f;
    }
}

// ---------- main: GEMM + softmax/argmax/marginal (+ fused gather if `fused`) ----------
// grid 2048 = 1024 row-tiles (64 rows) x 2 groups; 512 thr = 8 waves.
// K-loop = r12's proven schedule: ISSUE(c+1) -> vmcnt(3) -> raw s_barrier -> COMPUTE(c).
__global__ __launch_bounds__(512, 4) void vq_main(
    const short* Hbf, const int* __restrict__ mask,
    const float* __restrict__ gumbel, const short* __restrict__ Wf,
    const float* __restrict__ bias, const float* __restrict__ cv,
    int* __restrict__ idxW, float* __restrict__ marg,
    int fused, float* __restrict__ out)
{
    __shared__ __align__(16) char smem[3 * BUFB];     // 72 KB: 3 chunk buffers
    __shared__ float    red_s[256];
    __shared__ unsigned red_k[256];
    __shared__ float    wrowS[64];
    __shared__ int      idxf[64];

    const int tid = threadIdx.x;
    const int l   = tid & 63, wid = tid >> 6;
    const int rh  = wid >> 2, hc = wid & 3;
    const int g   = blockIdx.x & 1;
    const int T   = blockIdx.x >> 1;
    const int n0  = T * 64;
    const int q   = l >> 4,  ln = l & 15;

    // hoisted per-lane DMA source base pointers (chunk t=0); +t*1024 B per chunk
    const short* gsrc0[3];
#pragma unroll
    for (int j = 0; j < 3; ++j) {
        const int k = wid * 3 + j;
        if (k < 4) gsrc0[j] = Hbf + (size_t)((2 * T + (k >> 1)) * 32 + (k & 1) * 16) * 512 + (size_t)l * 8;
        else       gsrc0[j] = Wf  + (size_t)((g * 20 + (k - 4)) * 16) * 512 + (size_t)l * 8;
    }

#define ISSUE(t_, b_)                                                          \
    { _Pragma("unroll")                                                        \
      for (int j = 0; j < 3; ++j) {                                            \
          const int k = wid * 3 + j;                                           \
          const short* gsrc = (const short*)((const char*)gsrc0[j] + ((t_) << 10)); \
          char* ldst = smem + (b_)*BUFB + k * 1024;                            \
          __builtin_amdgcn_global_load_lds((const glb_void*)gsrc, (lds_void*)ldst, 16, 0, 0); \
      } }

    f32x4 acc[2][5];
    const f32x4 vzero = {0.f, 0.f, 0.f, 0.f};
#pragma unroll
    for (int a = 0; a < 2; ++a)
#pragma unroll
        for (int b = 0; b < 5; ++b) acc[a][b] = vzero;

#define COMPUTE(b_)                                                            \
    { const char* bb_ = smem + (b_)*BUFB;                                      \
      bf16x8 Ar[2], Br[5];                                                     \
      _Pragma("unroll")                                                        \
      for (int rf = 0; rf < 2; ++rf)                                           \
          Ar[rf] = *(const bf16x8*)(bb_ + (rh * 2 + rf) * 1024 + l * 16);      \
      _Pragma("unroll")                                                        \
      for (int cf = 0; cf < 5; ++cf)                                           \
          Br[cf] = *(const bf16x8*)(bb_ + 4096 + (hc * 5 + cf) * 1024 + l * 16); \
      __builtin_amdgcn_s_setprio(1);                                           \
      _Pragma("unroll")                                                        \
      for (int cf = 0; cf < 5; ++cf) {                                         \
          acc[0][cf] = __builtin_amdgcn_mfma_f32_16x16x32_bf16(Ar[0], Br[cf], acc[0][cf], 0, 0, 0); \
          acc[1][cf] = __builtin_amdgcn_mfma_f32_16x16x32_bf16(Ar[1], Br[cf], acc[1][cf], 0, 0, 0); } \
      __builtin_amdgcn_s_setprio(0); }

    ISSUE(0, 0)
#pragma unroll 1
    for (int c = 0; c < 15; ++c) {
        ISSUE(c + 1, (c + 1) % 3)
        asm volatile("s_waitcnt vmcnt(3)" ::: "memory");   // chunk c landed; c+1 in flight
        __builtin_amdgcn_sched_barrier(0);
        __builtin_amdgcn_s_barrier();                      // raw: no vmcnt(0) drain
        COMPUTE(c % 3)
    }
    asm volatile("s_waitcnt vmcnt(0)" ::: "memory");
    __builtin_amdgcn_sched_barrier(0);
    __builtin_amdgcn_s_barrier();
    COMPUTE(0)                                             // chunk 15 -> buf 0

    // ---- epilogue: bias + gumbel, no-max softmax (exp into acc), packed-key argmax ----
    float bb[5];
#pragma unroll
    for (int cf = 0; cf < 5; ++cf) bb[cf] = bias[g * KK + hc * 80 + 16 * cf + ln];

    float gum[8][5];
#pragma unroll
    for (int rf = 0; rf < 2; ++rf)
#pragma unroll
        for (int reg = 0; reg < 4; ++reg) {
            const int row = 32 * rh + 16 * rf + 4 * q + reg;
            const float* gp = gumbel + ((size_t)(n0 + row) * GG + g) * KK + hc * 80 + ln;
#pragma unroll
            for (int cf = 0; cf < 5; ++cf) gum[rf * 4 + reg][cf] = gp[16 * cf];
        }
    __builtin_amdgcn_sched_barrier(0);

#pragma unroll
    for (int cf = 0; cf < 5; ++cf)
#pragma unroll
        for (int rf = 0; rf < 2; ++rf) {
            acc[rf][cf][0] += bb[cf]; acc[rf][cf][1] += bb[cf];
            acc[rf][cf][2] += bb[cf]; acc[rf][cf][3] += bb[cf];
        }

#pragma unroll
    for (int rf = 0; rf < 2; ++rf) {
#pragma unroll
        for (int reg = 0; reg < 4; ++reg) {
            const int row = 32 * rh + 16 * rf + 4 * q + reg;
            float s = 0.f, zm = -3.0e38f;
            int zi = 0;
#pragma unroll
            for (int cf = 0; cf < 5; ++cf) {
                float v = acc[rf][cf][reg];
                float z = v + gum[rf * 4 + reg][cf];
                if (z > zm) { zm = z; zi = hc * 80 + 16 * cf + ln; }  // in-lane: exact, first-index
                float e = __expf(v);
                s += e;
                acc[rf][cf][reg] = e;              // reuse in marginal
            }
            // key: ordered-float top 23 bits | (511 - zi) -> u32 max == argmax w/ low-index ties
            unsigned key = (ordf(zm) & 0xFFFFFE00u) | (unsigned)(511 - zi);
#pragma unroll
            for (int d = 1; d <= 8; d <<= 1) {
                s += __shfl_xor(s, d);
                unsigned ko = (unsigned)__shfl_xor((int)key, d);
                key = key > ko ? key : ko;
            }
            if (ln == 0) {
                const int base = row * 4 + hc;
                red_s[base] = s;
                red_k[base] = key;
            }
        }
    }
    __syncthreads();

    if (tid < 64) {
        const int b0 = tid * 4;
        float Z = red_s[b0] + red_s[b0 + 1] + red_s[b0 + 2] + red_s[b0 + 3];
        unsigned km = red_k[b0];
        km = km > red_k[b0 + 1] ? km : red_k[b0 + 1];
        km = km > red_k[b0 + 2] ? km : red_k[b0 + 2];
        km = km > red_k[b0 + 3] ? km : red_k[b0 + 3];
        const int ib = 511 - (int)(km & 511u);
        idxf[tid]  = ib;
        if (!fused) idxW[(size_t)(n0 + tid) * GG + g] = ib;
        wrowS[tid] = ((mask[n0 + tid] != 0) ? 1.0f : 0.0f) / Z;
    }
    __syncthreads();

    // ---- marginal (acc holds exp) ----
    float cs[5] = {0.f, 0.f, 0.f, 0.f, 0.f};
#pragma unroll
    for (int rf = 0; rf < 2; ++rf) {
#pragma unroll
        for (int reg = 0; reg < 4; ++reg) {
            const int row = 32 * rh + 16 * rf + 4 * q + reg;
            const float wv = wrowS[row];
#pragma unroll
            for (int cf = 0; cf < 5; ++cf)
                cs[cf] += acc[rf][cf][reg] * wv;
        }
    }
    {
        float* mc = marg + (size_t)(blockIdx.x & (NCPY - 1)) * (GG * KK);
#pragma unroll
        for (int cf = 0; cf < 5; ++cf) {
            float v = cs[cf];
            v += __shfl_xor(v, 16);
            v += __shfl_xor(v, 32);
            if (l < 16) atomicAdd(&mc[g * KK + hc * 80 + 16 * cf + l], v);
        }
    }

    // ---- fused codevector gather (Path A only: out does NOT alias Hbf) ----
    if (fused) {
#pragma unroll
        for (int i = 0; i < 4; ++i) {
            const int e = tid + 512 * i;           // 2048 float4: 64 rows x 32
            const int row = e >> 5, d4 = e & 31;
            const float4 v = ((const float4*)cv)[((size_t)g * KK + idxf[row]) * 32 + d4];
            ((float4*)(out + (size_t)(n0 + row) * 256 + g * DPG))[d4] = v;
        }
    }
}

// ---------- gather (blocks >=1, Path B) + finalize (block 0, both paths) ----------
__global__ __launch_bounds__(256) void gather_fin(
    const int* __restrict__ idxW, const float* __restrict__ cv,
    float* __restrict__ out,
    const int* __restrict__ mask, const float* __restrict__ marg,
    float* __restrict__ perp_out)
{
    const int tid = threadIdx.x;
    if (blockIdx.x == 0) {
        __shared__ float red[256];
        __shared__ float hg[GG];
        int cnt = 0;
        for (int n = tid; n < NN; n += 256) cnt += (mask[n] != 0) ? 1 : 0;
        red[tid] = (float)cnt;
        __syncthreads();
        for (int s = 128; s > 0; s >>= 1) {
            if (tid < s) red[tid] += red[tid + s];
            __syncthreads();
        }
        const float invc = 1.0f / red[0];
        __syncthreads();
        for (int g = 0; g < GG; ++g) {
            float h = 0.0f;
            for (int c = tid; c < KK; c += 256) {
                float m = 0.f;
#pragma unroll
                for (int x = 0; x < NCPY; ++x) m += marg[x * (GG * KK) + g * KK + c];
                m *= invc;
                h += m * logf(m + EPSL);
            }
            red[tid] = h;
            __syncthreads();
            for (int s = 128; s > 0; s >>= 1) {
                if (tid < s) red[tid] += red[tid + s];
                __syncthreads();
            }
            if (tid == 0) hg[g] = red[0];
            __syncthreads();
        }
        if (tid == 0) perp_out[0] = expf(-hg[0]) + expf(-hg[1]);
        return;
    }
    const int e = (blockIdx.x - 1) * 256 + tid;       // 4,194,304 float4 slots
    const int n = e >> 6, s4 = e & 63, g = s4 >> 5, d4 = s4 & 31;
    const int idx = idxW[(size_t)n * GG + g];
    const float4 v = ((const float4*)cv)[((size_t)g * KK + idx) * 32 + d4];
    ((float4*)out)[e] = v;
}

extern "C" void kernel_launch(void* const* d_in, const int* in_sizes, int n_in,
                              void* d_out, int out_size, void* d_ws, size_t ws_size,
                              hipStream_t stream)
{
    const float* H      = (const float*)d_in[0];   // (32,2048,512) f32
    const int*   mask   = (const int*)d_in[1];     // (32,2048) bool->int32
    const float* gumbel = (const float*)d_in[2];   // (131072,320) f32
    const float* W      = (const float*)d_in[3];   // (640,512) f32
    const float* bias   = (const float*)d_in[4];   // (640,) f32
    const float* cv     = (const float*)d_in[5];   // (1,640,128) f32

    float*  out  = (float*)d_out;                  // 16,777,216 + 1 floats
    float*  marg = (float*)d_ws;                   // 8 copies x 640 f32 (20 KB)
    short*  Wf   = (short*)((char*)d_ws + 32768);  // 0.655 MB bf16 frags
    int*    idxW = (int*)((char*)d_ws + 32768 + 655360);  // 131072 ints

    const size_t hbf_off  = 2 * 1024 * 1024;
    const size_t hbf_need = hbf_off + (size_t)64 * 1024 * 1024;
    const int fused = (ws_size >= hbf_need) ? 1 : 0;
    short* Hbf = fused ? (short*)((char*)d_ws + hbf_off) : (short*)d_out;

    prep_all<<<16545, 256, 0, stream>>>(H, Hbf, W, Wf, marg);
    vq_main<<<2048, 512, 0, stream>>>(Hbf, mask, gumbel, Wf, bias, cv, idxW, marg,
                                      fused, out);
    gather_fin<<<fused ? 1 : 16385, 256, 0, stream>>>(idxW, cv, out, mask, marg,
                                                      out + (size_t)NN * GG * DPG);
}